// Round 1
// baseline (1018.243 us; speedup 1.0000x reference)
//
#include <hip/hip_runtime.h>

#define EPSV 1e-5f

// ---------------- weight transpose (to k-major layout Wt[k][f]) ----------------
__global__ __launch_bounds__(256) void transpose_all_k(
    const float* __restrict__ W1l, const float* __restrict__ W1r,
    const float* __restrict__ W2l, const float* __restrict__ W2r,
    const float* __restrict__ W3l, const float* __restrict__ W3r,
    float* __restrict__ W1lt, float* __restrict__ W1rt,
    float* __restrict__ W2lt, float* __restrict__ W2rt,
    float* __restrict__ W3lt, float* __restrict__ W3rt)
{
    int idx = blockIdx.x * 256 + threadIdx.x;
    if (idx < 128 * 128) {
        int o = idx >> 7, i = idx & 127;
        W1lt[i * 128 + o] = W1l[idx];
        W1rt[i * 128 + o] = W1r[idx];
        W2lt[i * 128 + o] = W2l[idx];
        W2rt[i * 128 + o] = W2r[idx];
    }
    if (idx < 64 * 128) {
        int o = idx >> 7, i = idx & 127;   // o < 64
        W3lt[i * 64 + o] = W3l[idx];
        W3rt[i * 64 + o] = W3r[idx];
    }
}

// ---------------- CSR build ----------------
__global__ __launch_bounds__(256) void degree_k(const int* __restrict__ dst,
                                                int* __restrict__ deg, int E)
{
    int e = blockIdx.x * 256 + threadIdx.x;
    if (e < E) atomicAdd(&deg[dst[e]], 1);
}

__global__ __launch_bounds__(256) void block_sums_k(const int* __restrict__ deg,
                                                    int* __restrict__ sums, int N)
{
    __shared__ int sd[256];
    int b = blockIdx.x, tid = threadIdx.x;
    int base = b * 1024 + tid * 4;
    int s = 0;
#pragma unroll
    for (int j = 0; j < 4; j++) { int i = base + j; if (i < N) s += deg[i]; }
    sd[tid] = s;
    __syncthreads();
    for (int off = 128; off > 0; off >>= 1) {
        if (tid < off) sd[tid] += sd[tid + off];
        __syncthreads();
    }
    if (tid == 0) sums[b] = sd[0];
}

__global__ __launch_bounds__(128) void scan_sums_k(const int* __restrict__ sums,
                                                   int* __restrict__ offs, int NB)
{
    __shared__ int sd[128];
    int tid = threadIdx.x;
    int v = (tid < NB) ? sums[tid] : 0;
    sd[tid] = v;
    __syncthreads();
    for (int off = 1; off < 128; off <<= 1) {
        int t = (tid >= off) ? sd[tid - off] : 0;
        __syncthreads();
        sd[tid] += t;
        __syncthreads();
    }
    if (tid < NB) offs[tid] = sd[tid] - v;   // exclusive
}

__global__ __launch_bounds__(256) void write_rowptr_k(const int* __restrict__ deg,
                                                      const int* __restrict__ offs,
                                                      int* __restrict__ row_ptr,
                                                      float* __restrict__ inv_deg,
                                                      int N, int E)
{
    __shared__ int sd[256];
    int b = blockIdx.x, tid = threadIdx.x;
    int base = b * 1024 + tid * 4;
    int d[4]; int ts = 0;
#pragma unroll
    for (int j = 0; j < 4; j++) { int i = base + j; d[j] = (i < N) ? deg[i] : 0; ts += d[j]; }
    sd[tid] = ts;
    __syncthreads();
    for (int off = 1; off < 256; off <<= 1) {
        int t = (tid >= off) ? sd[tid - off] : 0;
        __syncthreads();
        sd[tid] += t;
        __syncthreads();
    }
    int run = offs[b] + sd[tid] - ts;
#pragma unroll
    for (int j = 0; j < 4; j++) {
        int i = base + j;
        if (i < N) {
            row_ptr[i] = run;
            inv_deg[i] = 1.0f / (float)(d[j] > 0 ? d[j] : 1);
            run += d[j];
        }
    }
    if (b == 0 && tid == 0) row_ptr[N] = E;
}

__global__ __launch_bounds__(256) void fill_csr_k(const int* __restrict__ src,
                                                  const int* __restrict__ dst,
                                                  const int* __restrict__ row_ptr,
                                                  int* __restrict__ cursor,
                                                  int* __restrict__ col, int E)
{
    int e = blockIdx.x * 256 + threadIdx.x;
    if (e < E) {
        int d = dst[e];
        int p = row_ptr[d] + atomicAdd(&cursor[d], 1);
        col[p] = src[e];
    }
}

// ---------------- dual GEMM: t = x@Wl.T ; u = x@Wr.T + b  (HID=128 out) ----------------
// block 256 = 2 paths (l/r) x 2 node-subgroups(8) x 64 lanes; 16 nodes per block.
__global__ __launch_bounds__(256) void gemm_dual128(const float* __restrict__ x,
                                                    const float* __restrict__ Wlt,
                                                    const float* __restrict__ Wrt,
                                                    const float* __restrict__ b,
                                                    float* __restrict__ t,
                                                    float* __restrict__ u)
{
    __shared__ float xs[2048];  // 16 rows x 128
    int tid = threadIdx.x;
    int n0 = blockIdx.x * 16;
    const float4* xv = (const float4*)(x + (size_t)n0 * 128);
    float4* xsv = (float4*)xs;
    xsv[tid] = xv[tid];
    xsv[tid + 256] = xv[tid + 256];
    __syncthreads();

    int path = tid >> 7, sub = (tid >> 6) & 1, lane = tid & 63;
    const float* W = path ? Wrt : Wlt;
    float i0 = path ? b[lane] : 0.0f;
    float i1 = path ? b[lane + 64] : 0.0f;
    float acc0[8], acc1[8];
#pragma unroll
    for (int m = 0; m < 8; m++) { acc0[m] = i0; acc1[m] = i1; }

    const float4* xbase = (const float4*)(xs + sub * 1024);  // 8 rows
    for (int k4 = 0; k4 < 32; k4++) {
        float4 xr[8];
#pragma unroll
        for (int m = 0; m < 8; m++) xr[m] = xbase[m * 32 + k4];
#pragma unroll
        for (int kk = 0; kk < 4; kk++) {
            int k = k4 * 4 + kk;
            float w0 = W[k * 128 + lane];
            float w1 = W[k * 128 + lane + 64];
#pragma unroll
            for (int m = 0; m < 8; m++) {
                float xc = (kk == 0) ? xr[m].x : (kk == 1) ? xr[m].y : (kk == 2) ? xr[m].z : xr[m].w;
                acc0[m] += xc * w0;
                acc1[m] += xc * w1;
            }
        }
    }
    float* out = path ? u : t;
    int nb = n0 + sub * 8;
#pragma unroll
    for (int m = 0; m < 8; m++) {
        out[(size_t)(nb + m) * 128 + lane] = acc0[m];
        out[(size_t)(nb + m) * 128 + lane + 64] = acc1[m];
    }
}

// ---------------- dual GEMM for layer 3 (OUT=64): t3 = x@W3l.T ; u3 = x@W3r.T + b3 ----------------
__global__ __launch_bounds__(256) void gemm_dual64(const float* __restrict__ x,
                                                   const float* __restrict__ Wlt,
                                                   const float* __restrict__ Wrt,
                                                   const float* __restrict__ b,
                                                   float* __restrict__ t,
                                                   float* __restrict__ u)
{
    __shared__ float xs[2048];
    int tid = threadIdx.x;
    int n0 = blockIdx.x * 16;
    const float4* xv = (const float4*)(x + (size_t)n0 * 128);
    float4* xsv = (float4*)xs;
    xsv[tid] = xv[tid];
    xsv[tid + 256] = xv[tid + 256];
    __syncthreads();

    int path = tid >> 7, sub = (tid >> 6) & 1, lane = tid & 63;
    const float* W = path ? Wrt : Wlt;
    float init = path ? b[lane] : 0.0f;
    float acc[8];
#pragma unroll
    for (int m = 0; m < 8; m++) acc[m] = init;

    const float4* xbase = (const float4*)(xs + sub * 1024);
    for (int k4 = 0; k4 < 32; k4++) {
        float4 xr[8];
#pragma unroll
        for (int m = 0; m < 8; m++) xr[m] = xbase[m * 32 + k4];
#pragma unroll
        for (int kk = 0; kk < 4; kk++) {
            int k = k4 * 4 + kk;
            float w = W[k * 64 + lane];
#pragma unroll
            for (int m = 0; m < 8; m++) {
                float xc = (kk == 0) ? xr[m].x : (kk == 1) ? xr[m].y : (kk == 2) ? xr[m].z : xr[m].w;
                acc[m] += xc * w;
            }
        }
    }
    float* out = path ? u : t;
    int nb = n0 + sub * 8;
#pragma unroll
    for (int m = 0; m < 8; m++) out[(size_t)(nb + m) * 64 + lane] = acc[m];
}

// ---------------- aggregation + epilogue, layers 1/2: h = relu(bn(mean_aggr(t) + u)) ----------------
// one wave per node, float2 per lane (128 features)
__global__ __launch_bounds__(256) void aggr_bn_relu(const float* __restrict__ t,
                                                    const float* __restrict__ u,
                                                    const int* __restrict__ row_ptr,
                                                    const int* __restrict__ col,
                                                    const float* __restrict__ inv_deg,
                                                    const float* __restrict__ g,
                                                    const float* __restrict__ be,
                                                    const float* __restrict__ rm,
                                                    const float* __restrict__ rv,
                                                    float* __restrict__ out, int N)
{
    int tid = threadIdx.x;
    int n = blockIdx.x * 4 + (tid >> 6);
    int lane = tid & 63;
    if (n >= N) return;
    int j0 = row_ptr[n], j1 = row_ptr[n + 1];
    float ax = 0.0f, ay = 0.0f;
    const float2* tp = (const float2*)t;
    for (int j = j0; j < j1; j++) {
        int s = col[j];
        float2 v = tp[s * 64 + lane];
        ax += v.x; ay += v.y;
    }
    float id = inv_deg[n];
    float2 uv = ((const float2*)u)[n * 64 + lane];
    int f0 = lane * 2;
    float h0 = ax * id + uv.x;
    float h1 = ay * id + uv.y;
    float s0 = g[f0] * rsqrtf(rv[f0] + EPSV);
    float s1 = g[f0 + 1] * rsqrtf(rv[f0 + 1] + EPSV);
    h0 = (h0 - rm[f0]) * s0 + be[f0];
    h1 = (h1 - rm[f0 + 1]) * s1 + be[f0 + 1];
    h0 = fmaxf(h0, 0.0f);
    h1 = fmaxf(h1, 0.0f);
    float2 r; r.x = h0; r.y = h1;
    ((float2*)out)[n * 64 + lane] = r;
}

// ---------------- aggregation + log_softmax, layer 3 (64 features) ----------------
__global__ __launch_bounds__(256) void aggr_lsm(const float* __restrict__ t3,
                                                const float* __restrict__ u3,
                                                const int* __restrict__ row_ptr,
                                                const int* __restrict__ col,
                                                const float* __restrict__ inv_deg,
                                                float* __restrict__ out, int N)
{
    int tid = threadIdx.x;
    int n = blockIdx.x * 4 + (tid >> 6);
    int lane = tid & 63;
    if (n >= N) return;
    int j0 = row_ptr[n], j1 = row_ptr[n + 1];
    float acc = 0.0f;
    for (int j = j0; j < j1; j++) {
        int s = col[j];
        acc += t3[s * 64 + lane];
    }
    float h = acc * inv_deg[n] + u3[n * 64 + lane];
    float m = h;
    for (int off = 32; off > 0; off >>= 1) m = fmaxf(m, __shfl_xor(m, off));
    float e = __expf(h - m);
    float s = e;
    for (int off = 32; off > 0; off >>= 1) s += __shfl_xor(s, off);
    out[n * 64 + lane] = h - m - __logf(s);
}

// ---------------- launch ----------------
extern "C" void kernel_launch(void* const* d_in, const int* in_sizes, int n_in,
                              void* d_out, int out_size, void* d_ws, size_t ws_size,
                              hipStream_t stream)
{
    const float* x   = (const float*)d_in[0];
    const int*   src = (const int*)d_in[1];
    const int*   dst = (const int*)d_in[2];
    const float* W1l = (const float*)d_in[3];
    const float* W1r = (const float*)d_in[4];
    const float* b1  = (const float*)d_in[5];
    const float* g1  = (const float*)d_in[6];
    const float* be1 = (const float*)d_in[7];
    const float* rm1 = (const float*)d_in[8];
    const float* rv1 = (const float*)d_in[9];
    const float* W2l = (const float*)d_in[10];
    const float* W2r = (const float*)d_in[11];
    const float* b2  = (const float*)d_in[12];
    const float* g2  = (const float*)d_in[13];
    const float* be2 = (const float*)d_in[14];
    const float* rm2 = (const float*)d_in[15];
    const float* rv2 = (const float*)d_in[16];
    const float* W3l = (const float*)d_in[17];
    const float* W3r = (const float*)d_in[18];
    const float* b3  = (const float*)d_in[19];
    float* out = (float*)d_out;

    const int N = in_sizes[0] / 128;   // 100000
    const int E = in_sizes[1];         // 1600000

    char* w = (char*)d_ws;
    auto alloc = [&](size_t bytes) -> void* {
        void* p = (void*)w;
        w += (bytes + 255) & ~(size_t)255;
        return p;
    };
    float* A       = (float*)alloc((size_t)N * 128 * 4);
    float* B       = (float*)alloc((size_t)N * 128 * 4);
    float* C       = (float*)alloc((size_t)N * 128 * 4);
    int*   col     = (int*)alloc((size_t)E * 4);
    int*   row_ptr = (int*)alloc((size_t)(N + 1) * 4);
    int*   cursor  = (int*)alloc((size_t)N * 4);
    int*   degi    = (int*)alloc((size_t)N * 4);
    float* inv_deg = (float*)alloc((size_t)N * 4);
    int*   bsums   = (int*)alloc(1024);
    int*   boffs   = (int*)alloc(1024);
    float* W1lt = (float*)alloc(65536);
    float* W1rt = (float*)alloc(65536);
    float* W2lt = (float*)alloc(65536);
    float* W2rt = (float*)alloc(65536);
    float* W3lt = (float*)alloc(32768);
    float* W3rt = (float*)alloc(32768);

    hipMemsetAsync(degi, 0, (size_t)N * 4, stream);
    hipMemsetAsync(cursor, 0, (size_t)N * 4, stream);

    transpose_all_k<<<64, 256, 0, stream>>>(W1l, W1r, W2l, W2r, W3l, W3r,
                                            W1lt, W1rt, W2lt, W2rt, W3lt, W3rt);

    degree_k<<<(E + 255) / 256, 256, 0, stream>>>(dst, degi, E);
    int NB = (N + 1023) / 1024;   // 98
    block_sums_k<<<NB, 256, 0, stream>>>(degi, bsums, N);
    scan_sums_k<<<1, 128, 0, stream>>>(bsums, boffs, NB);
    write_rowptr_k<<<NB, 256, 0, stream>>>(degi, boffs, row_ptr, inv_deg, N, E);
    fill_csr_k<<<(E + 255) / 256, 256, 0, stream>>>(src, dst, row_ptr, cursor, col, E);

    int GG = N / 16;          // 6250 (N divisible by 16)
    int GA = (N + 3) / 4;     // 25000

    // layer 1
    gemm_dual128<<<GG, 256, 0, stream>>>(x, W1lt, W1rt, b1, A, B);
    aggr_bn_relu<<<GA, 256, 0, stream>>>(A, B, row_ptr, col, inv_deg, g1, be1, rm1, rv1, C, N);
    // layer 2
    gemm_dual128<<<GG, 256, 0, stream>>>(C, W2lt, W2rt, b2, A, B);
    aggr_bn_relu<<<GA, 256, 0, stream>>>(A, B, row_ptr, col, inv_deg, g2, be2, rm2, rv2, C, N);
    // layer 3
    gemm_dual64<<<GG, 256, 0, stream>>>(C, W3lt, W3rt, b3, A, B);
    aggr_lsm<<<GA, 256, 0, stream>>>(A, B, row_ptr, col, inv_deg, out, N);
}

// Round 2
// 783.855 us; speedup vs baseline: 1.2990x; 1.2990x over previous
//
#include <hip/hip_runtime.h>

#define EPSV 1e-5f

// ---- bf16 helpers (manual RNE, no API dependency) ----
__device__ __forceinline__ unsigned f2bf_pair(float a, float b) {
    unsigned ua = __float_as_uint(a);
    unsigned ub = __float_as_uint(b);
    ua = (ua + 0x7fffu + ((ua >> 16) & 1u)) >> 16;
    ub = (ub + 0x7fffu + ((ub >> 16) & 1u)) >> 16;
    return ua | (ub << 16);
}
__device__ __forceinline__ unsigned short f2bf(float a) {
    unsigned ua = __float_as_uint(a);
    return (unsigned short)((ua + 0x7fffu + ((ua >> 16) & 1u)) >> 16);
}
__device__ __forceinline__ float bf_lo(unsigned v) { return __uint_as_float(v << 16); }
__device__ __forceinline__ float bf_hi(unsigned v) { return __uint_as_float(v & 0xffff0000u); }

// ---------------- weight transpose (to k-major layout Wt[k][f]) ----------------
__global__ __launch_bounds__(256) void transpose_all_k(
    const float* __restrict__ W1l, const float* __restrict__ W1r,
    const float* __restrict__ W2l, const float* __restrict__ W2r,
    const float* __restrict__ W3l, const float* __restrict__ W3r,
    float* __restrict__ W1lt, float* __restrict__ W1rt,
    float* __restrict__ W2lt, float* __restrict__ W2rt,
    float* __restrict__ W3lt, float* __restrict__ W3rt)
{
    int idx = blockIdx.x * 256 + threadIdx.x;
    if (idx < 128 * 128) {
        int o = idx >> 7, i = idx & 127;
        W1lt[i * 128 + o] = W1l[idx];
        W1rt[i * 128 + o] = W1r[idx];
        W2lt[i * 128 + o] = W2l[idx];
        W2rt[i * 128 + o] = W2r[idx];
    }
    if (idx < 64 * 128) {
        int o = idx >> 7, i = idx & 127;   // o < 64
        W3lt[i * 64 + o] = W3l[idx];
        W3rt[i * 64 + o] = W3r[idx];
    }
}

// ---------------- CSR build ----------------
__global__ __launch_bounds__(256) void degree_k(const int* __restrict__ dst,
                                                int* __restrict__ deg, int E)
{
    int e = blockIdx.x * 256 + threadIdx.x;
    if (e < E) atomicAdd(&deg[dst[e]], 1);
}

__global__ __launch_bounds__(256) void block_sums_k(const int* __restrict__ deg,
                                                    int* __restrict__ sums, int N)
{
    __shared__ int sd[256];
    int b = blockIdx.x, tid = threadIdx.x;
    int base = b * 1024 + tid * 4;
    int s = 0;
#pragma unroll
    for (int j = 0; j < 4; j++) { int i = base + j; if (i < N) s += deg[i]; }
    sd[tid] = s;
    __syncthreads();
    for (int off = 128; off > 0; off >>= 1) {
        if (tid < off) sd[tid] += sd[tid + off];
        __syncthreads();
    }
    if (tid == 0) sums[b] = sd[0];
}

__global__ __launch_bounds__(128) void scan_sums_k(const int* __restrict__ sums,
                                                   int* __restrict__ offs, int NB)
{
    __shared__ int sd[128];
    int tid = threadIdx.x;
    int v = (tid < NB) ? sums[tid] : 0;
    sd[tid] = v;
    __syncthreads();
    for (int off = 1; off < 128; off <<= 1) {
        int t = (tid >= off) ? sd[tid - off] : 0;
        __syncthreads();
        sd[tid] += t;
        __syncthreads();
    }
    if (tid < NB) offs[tid] = sd[tid] - v;   // exclusive
}

__global__ __launch_bounds__(256) void write_rowptr_k(const int* __restrict__ deg,
                                                      const int* __restrict__ offs,
                                                      int* __restrict__ row_ptr,
                                                      float* __restrict__ inv_deg,
                                                      int N, int E)
{
    __shared__ int sd[256];
    int b = blockIdx.x, tid = threadIdx.x;
    int base = b * 1024 + tid * 4;
    int d[4]; int ts = 0;
#pragma unroll
    for (int j = 0; j < 4; j++) { int i = base + j; d[j] = (i < N) ? deg[i] : 0; ts += d[j]; }
    sd[tid] = ts;
    __syncthreads();
    for (int off = 1; off < 256; off <<= 1) {
        int t = (tid >= off) ? sd[tid - off] : 0;
        __syncthreads();
        sd[tid] += t;
        __syncthreads();
    }
    int run = offs[b] + sd[tid] - ts;
#pragma unroll
    for (int j = 0; j < 4; j++) {
        int i = base + j;
        if (i < N) {
            row_ptr[i] = run;
            inv_deg[i] = 1.0f / (float)(d[j] > 0 ? d[j] : 1);
            run += d[j];
        }
    }
    if (b == 0 && tid == 0) row_ptr[N] = E;
}

__global__ __launch_bounds__(256) void fill_csr_k(const int* __restrict__ src,
                                                  const int* __restrict__ dst,
                                                  const int* __restrict__ row_ptr,
                                                  int* __restrict__ cursor,
                                                  int* __restrict__ col, int E)
{
    int e = blockIdx.x * 256 + threadIdx.x;
    if (e < E) {
        int d = dst[e];
        int p = row_ptr[d] + atomicAdd(&cursor[d], 1);
        col[p] = src[e];
    }
}

// ---------------- dual GEMM: t = bf16(x@Wl.T) ; u = x@Wr.T + b  (HID=128 out) ----------------
// block 256 = 2 paths (l/r) x 2 node-subgroups(8) x 64 lanes; 16 nodes per block.
// Lane owns feature pair (2*lane, 2*lane+1) via float2 weight loads.
__global__ __launch_bounds__(256) void gemm_dual128(const float* __restrict__ x,
                                                    const float* __restrict__ Wlt,
                                                    const float* __restrict__ Wrt,
                                                    const float* __restrict__ b,
                                                    unsigned* __restrict__ t,   // bf16x2 packed
                                                    float* __restrict__ u)
{
    __shared__ float xs[2048];  // 16 rows x 128
    int tid = threadIdx.x;
    int n0 = blockIdx.x * 16;
    const float4* xv = (const float4*)(x + (size_t)n0 * 128);
    float4* xsv = (float4*)xs;
    xsv[tid] = xv[tid];
    xsv[tid + 256] = xv[tid + 256];
    __syncthreads();

    int path = tid >> 7, sub = (tid >> 6) & 1, lane = tid & 63;
    const float* W = path ? Wrt : Wlt;
    float i0 = path ? b[2 * lane] : 0.0f;
    float i1 = path ? b[2 * lane + 1] : 0.0f;
    float acc0[8], acc1[8];
#pragma unroll
    for (int m = 0; m < 8; m++) { acc0[m] = i0; acc1[m] = i1; }

    const float4* xbase = (const float4*)(xs + sub * 1024);  // 8 rows
    for (int k4 = 0; k4 < 32; k4++) {
        float4 xr[8];
#pragma unroll
        for (int m = 0; m < 8; m++) xr[m] = xbase[m * 32 + k4];
#pragma unroll
        for (int kk = 0; kk < 4; kk++) {
            int k = k4 * 4 + kk;
            float2 w = ((const float2*)(W + k * 128))[lane];
#pragma unroll
            for (int m = 0; m < 8; m++) {
                float xc = (kk == 0) ? xr[m].x : (kk == 1) ? xr[m].y : (kk == 2) ? xr[m].z : xr[m].w;
                acc0[m] += xc * w.x;
                acc1[m] += xc * w.y;
            }
        }
    }
    int nb = n0 + sub * 8;
    if (path) {
        float2* u2 = (float2*)u;
#pragma unroll
        for (int m = 0; m < 8; m++) {
            float2 r; r.x = acc0[m]; r.y = acc1[m];
            u2[(size_t)(nb + m) * 64 + lane] = r;
        }
    } else {
#pragma unroll
        for (int m = 0; m < 8; m++)
            t[(size_t)(nb + m) * 64 + lane] = f2bf_pair(acc0[m], acc1[m]);
    }
}

// ---------------- dual GEMM for layer 3 (OUT=64): t3 = bf16(x@W3l.T) ; u3 = x@W3r.T + b3 ----------------
__global__ __launch_bounds__(256) void gemm_dual64(const float* __restrict__ x,
                                                   const float* __restrict__ Wlt,
                                                   const float* __restrict__ Wrt,
                                                   const float* __restrict__ b,
                                                   unsigned short* __restrict__ t,  // bf16
                                                   float* __restrict__ u)
{
    __shared__ float xs[2048];
    int tid = threadIdx.x;
    int n0 = blockIdx.x * 16;
    const float4* xv = (const float4*)(x + (size_t)n0 * 128);
    float4* xsv = (float4*)xs;
    xsv[tid] = xv[tid];
    xsv[tid + 256] = xv[tid + 256];
    __syncthreads();

    int path = tid >> 7, sub = (tid >> 6) & 1, lane = tid & 63;
    const float* W = path ? Wrt : Wlt;
    float init = path ? b[lane] : 0.0f;
    float acc[8];
#pragma unroll
    for (int m = 0; m < 8; m++) acc[m] = init;

    const float4* xbase = (const float4*)(xs + sub * 1024);
    for (int k4 = 0; k4 < 32; k4++) {
        float4 xr[8];
#pragma unroll
        for (int m = 0; m < 8; m++) xr[m] = xbase[m * 32 + k4];
#pragma unroll
        for (int kk = 0; kk < 4; kk++) {
            int k = k4 * 4 + kk;
            float w = W[k * 64 + lane];
#pragma unroll
            for (int m = 0; m < 8; m++) {
                float xc = (kk == 0) ? xr[m].x : (kk == 1) ? xr[m].y : (kk == 2) ? xr[m].z : xr[m].w;
                acc[m] += xc * w;
            }
        }
    }
    int nb = n0 + sub * 8;
    if (path) {
#pragma unroll
        for (int m = 0; m < 8; m++) u[(size_t)(nb + m) * 64 + lane] = acc[m];
    } else {
#pragma unroll
        for (int m = 0; m < 8; m++) t[(size_t)(nb + m) * 64 + lane] = f2bf(acc[m]);
    }
}

// ---------------- aggregation + epilogue, layers 1/2: h = relu(bn(mean_aggr(t) + u)) ----------------
// one wave per node; lane holds feats (2*lane, 2*lane+1); t is packed bf16x2.
// neighbor loop unrolled x4 for memory-level parallelism.
__global__ __launch_bounds__(256) void aggr_bn_relu(const unsigned* __restrict__ t,
                                                    const float* __restrict__ u,
                                                    const int* __restrict__ row_ptr,
                                                    const int* __restrict__ col,
                                                    const float* __restrict__ inv_deg,
                                                    const float* __restrict__ g,
                                                    const float* __restrict__ be,
                                                    const float* __restrict__ rm,
                                                    const float* __restrict__ rv,
                                                    float* __restrict__ out, int N)
{
    int tid = threadIdx.x;
    int n = blockIdx.x * 4 + (tid >> 6);
    int lane = tid & 63;
    if (n >= N) return;
    int j0 = row_ptr[n], j1 = row_ptr[n + 1];
    float ax = 0.0f, ay = 0.0f;
    int j = j0;
    for (; j + 4 <= j1; j += 4) {
        int s0 = col[j], s1 = col[j + 1], s2 = col[j + 2], s3 = col[j + 3];
        unsigned v0 = t[s0 * 64 + lane];
        unsigned v1 = t[s1 * 64 + lane];
        unsigned v2 = t[s2 * 64 + lane];
        unsigned v3 = t[s3 * 64 + lane];
        ax += bf_lo(v0) + bf_lo(v1) + bf_lo(v2) + bf_lo(v3);
        ay += bf_hi(v0) + bf_hi(v1) + bf_hi(v2) + bf_hi(v3);
    }
    for (; j < j1; j++) {
        unsigned v = t[col[j] * 64 + lane];
        ax += bf_lo(v); ay += bf_hi(v);
    }
    float id = inv_deg[n];
    float2 uv = ((const float2*)u)[(size_t)n * 64 + lane];
    int f0 = lane * 2;
    float h0 = ax * id + uv.x;
    float h1 = ay * id + uv.y;
    float s0 = g[f0] * rsqrtf(rv[f0] + EPSV);
    float s1 = g[f0 + 1] * rsqrtf(rv[f0 + 1] + EPSV);
    h0 = (h0 - rm[f0]) * s0 + be[f0];
    h1 = (h1 - rm[f0 + 1]) * s1 + be[f0 + 1];
    h0 = fmaxf(h0, 0.0f);
    h1 = fmaxf(h1, 0.0f);
    float2 r; r.x = h0; r.y = h1;
    ((float2*)out)[(size_t)n * 64 + lane] = r;
}

// ---------------- aggregation + log_softmax, layer 3 (64 features, bf16 t3) ----------------
__global__ __launch_bounds__(256) void aggr_lsm(const unsigned short* __restrict__ t3,
                                                const float* __restrict__ u3,
                                                const int* __restrict__ row_ptr,
                                                const int* __restrict__ col,
                                                const float* __restrict__ inv_deg,
                                                float* __restrict__ out, int N)
{
    int tid = threadIdx.x;
    int n = blockIdx.x * 4 + (tid >> 6);
    int lane = tid & 63;
    if (n >= N) return;
    int j0 = row_ptr[n], j1 = row_ptr[n + 1];
    float acc = 0.0f;
    int j = j0;
    for (; j + 4 <= j1; j += 4) {
        int s0 = col[j], s1 = col[j + 1], s2 = col[j + 2], s3 = col[j + 3];
        float a0 = __uint_as_float((unsigned)t3[s0 * 64 + lane] << 16);
        float a1 = __uint_as_float((unsigned)t3[s1 * 64 + lane] << 16);
        float a2 = __uint_as_float((unsigned)t3[s2 * 64 + lane] << 16);
        float a3 = __uint_as_float((unsigned)t3[s3 * 64 + lane] << 16);
        acc += a0 + a1 + a2 + a3;
    }
    for (; j < j1; j++)
        acc += __uint_as_float((unsigned)t3[col[j] * 64 + lane] << 16);
    float h = acc * inv_deg[n] + u3[(size_t)n * 64 + lane];
    float m = h;
    for (int off = 32; off > 0; off >>= 1) m = fmaxf(m, __shfl_xor(m, off));
    float e = __expf(h - m);
    float s = e;
    for (int off = 32; off > 0; off >>= 1) s += __shfl_xor(s, off);
    out[(size_t)n * 64 + lane] = h - m - __logf(s);
}

// ---------------- launch ----------------
extern "C" void kernel_launch(void* const* d_in, const int* in_sizes, int n_in,
                              void* d_out, int out_size, void* d_ws, size_t ws_size,
                              hipStream_t stream)
{
    const float* x   = (const float*)d_in[0];
    const int*   src = (const int*)d_in[1];
    const int*   dst = (const int*)d_in[2];
    const float* W1l = (const float*)d_in[3];
    const float* W1r = (const float*)d_in[4];
    const float* b1  = (const float*)d_in[5];
    const float* g1  = (const float*)d_in[6];
    const float* be1 = (const float*)d_in[7];
    const float* rm1 = (const float*)d_in[8];
    const float* rv1 = (const float*)d_in[9];
    const float* W2l = (const float*)d_in[10];
    const float* W2r = (const float*)d_in[11];
    const float* b2  = (const float*)d_in[12];
    const float* g2  = (const float*)d_in[13];
    const float* be2 = (const float*)d_in[14];
    const float* rm2 = (const float*)d_in[15];
    const float* rv2 = (const float*)d_in[16];
    const float* W3l = (const float*)d_in[17];
    const float* W3r = (const float*)d_in[18];
    const float* b3  = (const float*)d_in[19];
    float* out = (float*)d_out;

    const int N = in_sizes[0] / 128;   // 100000
    const int E = in_sizes[1];         // 1600000

    char* w = (char*)d_ws;
    auto alloc = [&](size_t bytes) -> void* {
        void* p = (void*)w;
        w += (bytes + 255) & ~(size_t)255;
        return p;
    };
    unsigned* A    = (unsigned*)alloc((size_t)N * 64 * 4);    // t (bf16x2) / t3 (bf16)
    float* B       = (float*)alloc((size_t)N * 128 * 4);      // u
    float* C       = (float*)alloc((size_t)N * 128 * 4);      // h
    int*   col     = (int*)alloc((size_t)E * 4);
    int*   row_ptr = (int*)alloc((size_t)(N + 1) * 4);
    int*   cursor  = (int*)alloc((size_t)N * 4);
    int*   degi    = (int*)alloc((size_t)N * 4);
    float* inv_deg = (float*)alloc((size_t)N * 4);
    int*   bsums   = (int*)alloc(1024);
    int*   boffs   = (int*)alloc(1024);
    float* W1lt = (float*)alloc(65536);
    float* W1rt = (float*)alloc(65536);
    float* W2lt = (float*)alloc(65536);
    float* W2rt = (float*)alloc(65536);
    float* W3lt = (float*)alloc(32768);
    float* W3rt = (float*)alloc(32768);

    hipMemsetAsync(degi, 0, (size_t)N * 4, stream);
    hipMemsetAsync(cursor, 0, (size_t)N * 4, stream);

    transpose_all_k<<<64, 256, 0, stream>>>(W1l, W1r, W2l, W2r, W3l, W3r,
                                            W1lt, W1rt, W2lt, W2rt, W3lt, W3rt);

    degree_k<<<(E + 255) / 256, 256, 0, stream>>>(dst, degi, E);
    int NB = (N + 1023) / 1024;   // 98
    block_sums_k<<<NB, 256, 0, stream>>>(degi, bsums, N);
    scan_sums_k<<<1, 128, 0, stream>>>(bsums, boffs, NB);
    write_rowptr_k<<<NB, 256, 0, stream>>>(degi, boffs, row_ptr, inv_deg, N, E);
    fill_csr_k<<<(E + 255) / 256, 256, 0, stream>>>(src, dst, row_ptr, cursor, col, E);

    int GG = N / 16;          // 6250 (N divisible by 16)
    int GA = (N + 3) / 4;     // 25000

    // layer 1
    gemm_dual128<<<GG, 256, 0, stream>>>(x, W1lt, W1rt, b1, A, B);
    aggr_bn_relu<<<GA, 256, 0, stream>>>(A, B, row_ptr, col, inv_deg, g1, be1, rm1, rv1, C, N);
    // layer 2
    gemm_dual128<<<GG, 256, 0, stream>>>(C, W2lt, W2rt, b2, A, B);
    aggr_bn_relu<<<GA, 256, 0, stream>>>(A, B, row_ptr, col, inv_deg, g2, be2, rm2, rv2, C, N);
    // layer 3
    gemm_dual64<<<GG, 256, 0, stream>>>(C, W3lt, W3rt, b3, (unsigned short*)A, B);
    aggr_lsm<<<GA, 256, 0, stream>>>((unsigned short*)A, B, row_ptr, col, inv_deg, out, N);
}

// Round 4
// 586.476 us; speedup vs baseline: 1.7362x; 1.3366x over previous
//
#include <hip/hip_runtime.h>

#define EPSV 1e-5f

typedef __attribute__((ext_vector_type(8))) short short8;
typedef __attribute__((ext_vector_type(4))) float floatx4;

// ---- bf16 helpers (manual RNE) ----
__device__ __forceinline__ unsigned f2bf_pair(float a, float b) {
    unsigned ua = __float_as_uint(a);
    unsigned ub = __float_as_uint(b);
    ua = (ua + 0x7fffu + ((ua >> 16) & 1u)) >> 16;
    ub = (ub + 0x7fffu + ((ub >> 16) & 1u)) >> 16;
    return ua | (ub << 16);
}
__device__ __forceinline__ float bf_lo(unsigned v) { return __uint_as_float(v << 16); }
__device__ __forceinline__ float bf_hi(unsigned v) { return __uint_as_float(v & 0xffff0000u); }

__device__ __forceinline__ short8 cvt8(float4 lo, float4 hi) {
    union { short8 s; unsigned d[4]; } r;
    r.d[0] = f2bf_pair(lo.x, lo.y);
    r.d[1] = f2bf_pair(lo.z, lo.w);
    r.d[2] = f2bf_pair(hi.x, hi.y);
    r.d[3] = f2bf_pair(hi.z, hi.w);
    return r.s;
}

// ---------------- weight pre-pack into B-fragment order ----------------
// frag f = (w*4 + s)*nsub + i ; lane holds W[o][k..k+7] with
// o = (w&1)*(nsub*16) + i*16 + (lane&15), k = s*32 + (lane>>4)*8
__global__ __launch_bounds__(256) void pack_w_k(const float* __restrict__ Wl,
                                                const float* __restrict__ Wr,
                                                uint4* __restrict__ out, int nsub)
{
    int t = blockIdx.x * 256 + threadIdx.x;
    int lane = t & 63, f = t >> 6;
    int nf = 16 * nsub;
    if (f >= nf) return;
    int i = f % nsub, s = (f / nsub) & 3, w = f / (4 * nsub);
    const float* W = (w >= 2) ? Wr : Wl;
    int o = (w & 1) * (nsub * 16) + i * 16 + (lane & 15);
    int k = s * 32 + (lane >> 4) * 8;
    const float* p = W + o * 128 + k;
    union { uint4 u; unsigned d[4]; } r;
    r.d[0] = f2bf_pair(p[0], p[1]);
    r.d[1] = f2bf_pair(p[2], p[3]);
    r.d[2] = f2bf_pair(p[4], p[5]);
    r.d[3] = f2bf_pair(p[6], p[7]);
    out[f * 64 + lane] = r.u;
}

// ---------------- CSR build ----------------
__global__ __launch_bounds__(256) void degree_k(const int* __restrict__ dst,
                                                int* __restrict__ deg, int E)
{
    int e = blockIdx.x * 256 + threadIdx.x;
    if (e < E) atomicAdd(&deg[dst[e]], 1);
}

__global__ __launch_bounds__(256) void block_sums_k(const int* __restrict__ deg,
                                                    int* __restrict__ sums, int N)
{
    __shared__ int sd[256];
    int b = blockIdx.x, tid = threadIdx.x;
    int base = b * 1024 + tid * 4;
    int s = 0;
#pragma unroll
    for (int j = 0; j < 4; j++) { int i = base + j; if (i < N) s += deg[i]; }
    sd[tid] = s;
    __syncthreads();
    for (int off = 128; off > 0; off >>= 1) {
        if (tid < off) sd[tid] += sd[tid + off];
        __syncthreads();
    }
    if (tid == 0) sums[b] = sd[0];
}

__global__ __launch_bounds__(128) void scan_sums_k(const int* __restrict__ sums,
                                                   int* __restrict__ offs, int NB)
{
    __shared__ int sd[128];
    int tid = threadIdx.x;
    int v = (tid < NB) ? sums[tid] : 0;
    sd[tid] = v;
    __syncthreads();
    for (int off = 1; off < 128; off <<= 1) {
        int t = (tid >= off) ? sd[tid - off] : 0;
        __syncthreads();
        sd[tid] += t;
        __syncthreads();
    }
    if (tid < NB) offs[tid] = sd[tid] - v;   // exclusive
}

__global__ __launch_bounds__(256) void write_rowptr_k(const int* __restrict__ deg,
                                                      const int* __restrict__ offs,
                                                      int* __restrict__ row_ptr,
                                                      float* __restrict__ inv_deg,
                                                      int N, int E)
{
    __shared__ int sd[256];
    int b = blockIdx.x, tid = threadIdx.x;
    int base = b * 1024 + tid * 4;
    int d[4]; int ts = 0;
#pragma unroll
    for (int j = 0; j < 4; j++) { int i = base + j; d[j] = (i < N) ? deg[i] : 0; ts += d[j]; }
    sd[tid] = ts;
    __syncthreads();
    for (int off = 1; off < 256; off <<= 1) {
        int t = (tid >= off) ? sd[tid - off] : 0;
        __syncthreads();
        sd[tid] += t;
        __syncthreads();
    }
    int run = offs[b] + sd[tid] - ts;
#pragma unroll
    for (int j = 0; j < 4; j++) {
        int i = base + j;
        if (i < N) {
            row_ptr[i] = run;
            inv_deg[i] = 1.0f / (float)(d[j] > 0 ? d[j] : 1);
            run += d[j];
        }
    }
    if (b == 0 && tid == 0) row_ptr[N] = E;
}

__global__ __launch_bounds__(256) void fill_csr_k(const int* __restrict__ src,
                                                  const int* __restrict__ dst,
                                                  const int* __restrict__ row_ptr,
                                                  int* __restrict__ cursor,
                                                  int* __restrict__ col, int E)
{
    int e = blockIdx.x * 256 + threadIdx.x;
    if (e < E) {
        int d = dst[e];
        int p = row_ptr[d] + atomicAdd(&cursor[d], 1);
        col[p] = src[e];
    }
}

// ---------------- MFMA dual GEMM ----------------
// Computes TU[n][o] bf16, o in [0, NSUB*64): first half = x@Wl.T, second = x@Wr.T + b.
// Block: 64 nodes, 4 waves; wave w owns output cols [w*NSUB*16, (w+1)*NSUB*16).
template<bool INF32, int NSUB>
__global__ __launch_bounds__(256) void gemm_mfma(const void* __restrict__ xin,
                                                 const uint4* __restrict__ wpack,
                                                 const float* __restrict__ bias,
                                                 unsigned* __restrict__ TU, int N)
{
    constexpr int LDS_BYTES = INF32 ? 64 * 132 * 4 : 64 * 136 * 2;
    __shared__ char lds_raw[LDS_BYTES];
    float* ldsf = (float*)lds_raw;
    unsigned short* ldsh = (unsigned short*)lds_raw;

    int tid = threadIdx.x;
    int n0 = blockIdx.x * 64;

    // ---- stage X tile (64 rows) into padded LDS ----
    if (INF32) {
        const float4* src = (const float4*)xin;   // row = 32 float4
        int r = tid >> 5, c = tid & 31;
#pragma unroll
        for (int it = 0; it < 8; it++) {
            int row = it * 8 + r;
            int n = n0 + row; if (n >= N) n = N - 1;
            float4 v = src[(size_t)n * 32 + c];
            *(float4*)&ldsf[row * 132 + c * 4] = v;
        }
    } else {
        const uint4* src = (const uint4*)xin;     // row = 16 uint4 (128 bf16)
        int r = tid >> 4, c = tid & 15;
#pragma unroll
        for (int it = 0; it < 4; it++) {
            int row = it * 16 + r;
            int n = n0 + row; if (n >= N) n = N - 1;
            uint4 v = src[(size_t)n * 16 + c];
            *(uint4*)&ldsh[row * 136 + c * 8] = v;
        }
    }

    // ---- load B fragments (weights) into registers ----
    int wave = tid >> 6, lane = tid & 63;
    short8 bfr[4][NSUB];
#pragma unroll
    for (int s = 0; s < 4; s++)
#pragma unroll
        for (int i = 0; i < NSUB; i++)
            bfr[s][i] = *(const short8*)&wpack[((wave * 4 + s) * NSUB + i) * 64 + lane];

    __syncthreads();

    // ---- K loop ----
    floatx4 acc[4][NSUB];
#pragma unroll
    for (int ms = 0; ms < 4; ms++)
#pragma unroll
        for (int i = 0; i < NSUB; i++)
            acc[ms][i] = (floatx4)0.0f;

    int m = lane & 15, q = lane >> 4;
#pragma unroll
    for (int s = 0; s < 4; s++) {
        short8 af[4];
#pragma unroll
        for (int ms = 0; ms < 4; ms++) {
            if (INF32) {
                const float* p = &ldsf[(ms * 16 + m) * 132 + s * 32 + q * 8];
                float4 lo = *(const float4*)p;
                float4 hi = *(const float4*)(p + 4);
                af[ms] = cvt8(lo, hi);
            } else {
                af[ms] = *(const short8*)&ldsh[(ms * 16 + m) * 136 + s * 32 + q * 8];
            }
        }
#pragma unroll
        for (int ms = 0; ms < 4; ms++)
#pragma unroll
            for (int i = 0; i < NSUB; i++)
                acc[ms][i] = __builtin_amdgcn_mfma_f32_16x16x32_bf16(af[ms], bfr[s][i], acc[ms][i], 0, 0, 0);
    }

    // ---- bias on the r-path (waves 2,3) ----
    if (wave >= 2) {
#pragma unroll
        for (int i = 0; i < NSUB; i++) {
            float bv = bias[(wave - 2) * (NSUB * 16) + i * 16 + m];
#pragma unroll
            for (int ms = 0; ms < 4; ms++)
#pragma unroll
                for (int r = 0; r < 4; r++)
                    acc[ms][i][r] += bv;
        }
    }

    // ---- epilogue: pack col pairs via shfl, store bf16x2 ----
    constexpr int ROWDW = NSUB * 32;
#pragma unroll
    for (int ms = 0; ms < 4; ms++)
#pragma unroll
        for (int i = 0; i < NSUB; i++)
#pragma unroll
            for (int r = 0; r < 4; r++) {
                float v = acc[ms][i][r];
                float v2 = __shfl_xor(v, 1);
                if (!(lane & 1)) {
                    int row = ms * 16 + q * 4 + r;
                    int n = n0 + row;
                    if (n < N) {
                        int o = wave * (NSUB * 16) + i * 16 + m;   // even
                        TU[(size_t)n * ROWDW + (o >> 1)] = f2bf_pair(v, v2);
                    }
                }
            }
}

// ---------------- aggregation + BN + ReLU (layers 1/2) ----------------
// TU row = 128 dwords: t pairs [0,64), u pairs [64,128). Output: bf16 h [n][64 dwords].
__global__ __launch_bounds__(256) void aggr_bn_relu(const unsigned* __restrict__ TU,
                                                    const int* __restrict__ row_ptr,
                                                    const int* __restrict__ col,
                                                    const float* __restrict__ inv_deg,
                                                    const float* __restrict__ g,
                                                    const float* __restrict__ be,
                                                    const float* __restrict__ rm,
                                                    const float* __restrict__ rv,
                                                    unsigned* __restrict__ hout, int N)
{
    int tid = threadIdx.x;
    int n = blockIdx.x * 4 + (tid >> 6);
    int lane = tid & 63;
    if (n >= N) return;
    int j0 = row_ptr[n], j1 = row_ptr[n + 1];
    float ax = 0.0f, ay = 0.0f;
    int j = j0;
    for (; j + 4 <= j1; j += 4) {
        int s0 = col[j], s1 = col[j + 1], s2 = col[j + 2], s3 = col[j + 3];
        unsigned v0 = TU[(size_t)s0 * 128 + lane];
        unsigned v1 = TU[(size_t)s1 * 128 + lane];
        unsigned v2 = TU[(size_t)s2 * 128 + lane];
        unsigned v3 = TU[(size_t)s3 * 128 + lane];
        ax += bf_lo(v0) + bf_lo(v1) + bf_lo(v2) + bf_lo(v3);
        ay += bf_hi(v0) + bf_hi(v1) + bf_hi(v2) + bf_hi(v3);
    }
    for (; j < j1; j++) {
        unsigned v = TU[(size_t)col[j] * 128 + lane];
        ax += bf_lo(v); ay += bf_hi(v);
    }
    float id = inv_deg[n];
    unsigned uv = TU[(size_t)n * 128 + 64 + lane];
    int f0 = lane * 2;
    float h0 = ax * id + bf_lo(uv);
    float h1 = ay * id + bf_hi(uv);
    float s0 = g[f0] * rsqrtf(rv[f0] + EPSV);
    float s1 = g[f0 + 1] * rsqrtf(rv[f0 + 1] + EPSV);
    h0 = (h0 - rm[f0]) * s0 + be[f0];
    h1 = (h1 - rm[f0 + 1]) * s1 + be[f0 + 1];
    h0 = fmaxf(h0, 0.0f);
    h1 = fmaxf(h1, 0.0f);
    hout[(size_t)n * 64 + lane] = f2bf_pair(h0, h1);
}

// ---------------- aggregation + log_softmax (layer 3) ----------------
// TU3 row = 64 dwords: t3 pairs [0,32), u3 pairs [32,64).
// Lane lam handles FEATURE f = 2*(lam&31) + (lam>>5)  (dword p=lam&31, half=lam>>5).
// Reductions are over all 64 lanes so the lane->feature permutation is safe,
// but the STORE must use f, not lam (R3 bug: stored at lam -> permuted logits).
__global__ __launch_bounds__(256) void aggr_lsm(const unsigned* __restrict__ TU3,
                                                const int* __restrict__ row_ptr,
                                                const int* __restrict__ col,
                                                const float* __restrict__ inv_deg,
                                                float* __restrict__ out, int N)
{
    int tid = threadIdx.x;
    int n = blockIdx.x * 4 + (tid >> 6);
    int lane = tid & 63;
    if (n >= N) return;
    int p = lane & 31, hi = lane >> 5;
    int j0 = row_ptr[n], j1 = row_ptr[n + 1];
    float acc = 0.0f;
    int j = j0;
    for (; j + 4 <= j1; j += 4) {
        int s0 = col[j], s1 = col[j + 1], s2 = col[j + 2], s3 = col[j + 3];
        unsigned v0 = TU3[(size_t)s0 * 64 + p];
        unsigned v1 = TU3[(size_t)s1 * 64 + p];
        unsigned v2 = TU3[(size_t)s2 * 64 + p];
        unsigned v3 = TU3[(size_t)s3 * 64 + p];
        acc += (hi ? bf_hi(v0) : bf_lo(v0)) + (hi ? bf_hi(v1) : bf_lo(v1))
             + (hi ? bf_hi(v2) : bf_lo(v2)) + (hi ? bf_hi(v3) : bf_lo(v3));
    }
    for (; j < j1; j++) {
        unsigned v = TU3[(size_t)col[j] * 64 + p];
        acc += hi ? bf_hi(v) : bf_lo(v);
    }
    unsigned uv = TU3[(size_t)n * 64 + 32 + p];
    float h = acc * inv_deg[n] + (hi ? bf_hi(uv) : bf_lo(uv));
    float m = h;
    for (int off = 32; off > 0; off >>= 1) m = fmaxf(m, __shfl_xor(m, off));
    float e = __expf(h - m);
    float s = e;
    for (int off = 32; off > 0; off >>= 1) s += __shfl_xor(s, off);
    out[(size_t)n * 64 + 2 * p + hi] = h - m - __logf(s);   // store at FEATURE index
}

// ---------------- launch ----------------
extern "C" void kernel_launch(void* const* d_in, const int* in_sizes, int n_in,
                              void* d_out, int out_size, void* d_ws, size_t ws_size,
                              hipStream_t stream)
{
    const float* x   = (const float*)d_in[0];
    const int*   src = (const int*)d_in[1];
    const int*   dst = (const int*)d_in[2];
    const float* W1l = (const float*)d_in[3];
    const float* W1r = (const float*)d_in[4];
    const float* b1  = (const float*)d_in[5];
    const float* g1  = (const float*)d_in[6];
    const float* be1 = (const float*)d_in[7];
    const float* rm1 = (const float*)d_in[8];
    const float* rv1 = (const float*)d_in[9];
    const float* W2l = (const float*)d_in[10];
    const float* W2r = (const float*)d_in[11];
    const float* b2  = (const float*)d_in[12];
    const float* g2  = (const float*)d_in[13];
    const float* be2 = (const float*)d_in[14];
    const float* rm2 = (const float*)d_in[15];
    const float* rv2 = (const float*)d_in[16];
    const float* W3l = (const float*)d_in[17];
    const float* W3r = (const float*)d_in[18];
    const float* b3  = (const float*)d_in[19];
    float* out = (float*)d_out;

    const int N = in_sizes[0] / 128;   // 100000
    const int E = in_sizes[1];         // 1600000

    char* w = (char*)d_ws;
    auto alloc = [&](size_t bytes) -> void* {
        void* p = (void*)w;
        w += (bytes + 255) & ~(size_t)255;
        return p;
    };
    unsigned* TU   = (unsigned*)alloc((size_t)N * 128 * 4);   // [n][256] bf16 (also TU3 [n][128])
    unsigned* H    = (unsigned*)alloc((size_t)N * 64 * 4);    // [n][128] bf16 hidden
    int*   col     = (int*)alloc((size_t)E * 4);
    int*   row_ptr = (int*)alloc((size_t)(N + 1) * 4);
    int*   cursor  = (int*)alloc((size_t)N * 4);
    int*   degi    = (int*)alloc((size_t)N * 4);
    float* inv_deg = (float*)alloc((size_t)N * 4);
    int*   bsums   = (int*)alloc(1024);
    int*   boffs   = (int*)alloc(1024);
    uint4* Wp1 = (uint4*)alloc(65536);   // 64 frags x 1KB
    uint4* Wp2 = (uint4*)alloc(65536);
    uint4* Wp3 = (uint4*)alloc(32768);   // 32 frags

    hipMemsetAsync(degi, 0, (size_t)N * 4, stream);
    hipMemsetAsync(cursor, 0, (size_t)N * 4, stream);

    pack_w_k<<<16, 256, 0, stream>>>(W1l, W1r, Wp1, 4);
    pack_w_k<<<16, 256, 0, stream>>>(W2l, W2r, Wp2, 4);
    pack_w_k<<<8, 256, 0, stream>>>(W3l, W3r, Wp3, 2);

    degree_k<<<(E + 255) / 256, 256, 0, stream>>>(dst, degi, E);
    int NB = (N + 1023) / 1024;   // 98
    block_sums_k<<<NB, 256, 0, stream>>>(degi, bsums, N);
    scan_sums_k<<<1, 128, 0, stream>>>(bsums, boffs, NB);
    write_rowptr_k<<<NB, 256, 0, stream>>>(degi, boffs, row_ptr, inv_deg, N, E);
    fill_csr_k<<<(E + 255) / 256, 256, 0, stream>>>(src, dst, row_ptr, cursor, col, E);

    int GG = (N + 63) / 64;   // 1563
    int GA = (N + 3) / 4;     // 25000

    // layer 1 (fp32 input)
    gemm_mfma<true, 4><<<GG, 256, 0, stream>>>(x, Wp1, b1, TU, N);
    aggr_bn_relu<<<GA, 256, 0, stream>>>(TU, row_ptr, col, inv_deg, g1, be1, rm1, rv1, H, N);
    // layer 2 (bf16 input)
    gemm_mfma<false, 4><<<GG, 256, 0, stream>>>(H, Wp2, b2, TU, N);
    aggr_bn_relu<<<GA, 256, 0, stream>>>(TU, row_ptr, col, inv_deg, g2, be2, rm2, rv2, H, N);
    // layer 3 (bf16 input, 128 outputs)
    gemm_mfma<false, 2><<<GG, 256, 0, stream>>>(H, Wp3, b3, TU, N);
    aggr_lsm<<<GA, 256, 0, stream>>>(TU, row_ptr, col, inv_deg, out, N);
}